// Round 3
// baseline (12233.401 us; speedup 1.0000x reference)
//
#include <hip/hip_runtime.h>
#include <cstdint>
#include <cstddef>

namespace {
constexpr int Dh = 512;   // hidden / emb dim
constexpr int G3 = 1536;  // 3*Dh
constexpr int NB = 256;   // batch
constexpr int SL = 256;   // src len
constexpr int TL = 256;   // trg len
constexpr int NV = 512;   // vocab
}

typedef __attribute__((ext_vector_type(8))) short bf16x8;
typedef __attribute__((ext_vector_type(4))) float f32x4;

__device__ __forceinline__ unsigned short f2bf(float f) {
  unsigned int u = __float_as_uint(f);
  u = (u + 0x7FFFu + ((u >> 16) & 1u)) >> 16;  // RNE (finite, small values)
  return (unsigned short)u;
}
__device__ __forceinline__ float bf2f(unsigned short s) {
  return __uint_as_float(((unsigned int)s) << 16);
}

// f32 -> bf16 elementwise (optional relu), 4 elems/thread
__global__ __launch_bounds__(256) void cvt_bf16(const float* __restrict__ in,
                                                unsigned short* __restrict__ out,
                                                int n4, int relu) {
  int i = blockIdx.x * 256 + threadIdx.x;
  if (i >= n4) return;
  float4 v = ((const float4*)in)[i];
  if (relu) {
    v.x = fmaxf(v.x, 0.f); v.y = fmaxf(v.y, 0.f);
    v.z = fmaxf(v.z, 0.f); v.w = fmaxf(v.w, 0.f);
  }
  ushort4 o;
  o.x = f2bf(v.x); o.y = f2bf(v.y); o.z = f2bf(v.z); o.w = f2bf(v.w);
  ((ushort4*)out)[i] = o;
}

// C[M,N] = A(bf16) @ W(bf16 [N][K] native rows)^T-as-B + bias, K = 512.
// MFMA 16x16x32 bf16. 128x128 tile, BK=64, 256 threads = 4 waves (2x2 quadrants
// of 64x64). LDS k-chunked layout [kc][row][8] bf16 -> conflict-free b128 reads.
// AMODE 0: A row = Abase + idx[row]*K (embedding gather)
// AMODE 1: A row = Abase + ((row&255)*NB + (row>>8))*K (hb_all[t][b] for row=b*TL+t)
template <int AMODE, bool OUTBF16>
__global__ __launch_bounds__(256) void gemm_bf16(
    const unsigned short* __restrict__ Abase, const int* __restrict__ idx,
    const unsigned short* __restrict__ W, const float* __restrict__ bias,
    void* __restrict__ Cout, int N) {
  __shared__ unsigned short lds_a[8 * 128 * 8];  // 16 KB
  __shared__ unsigned short lds_b[8 * 128 * 8];  // 16 KB
  const int t = threadIdx.x;
  const int n0 = blockIdx.x * 128;
  const int m0 = blockIdx.y * 128;
  const int w = t >> 6, l = t & 63;
  const int mq = (w & 1) * 64, nq = (w >> 1) * 64;
  const int l15 = l & 15, lh = l >> 4;

  // staging: thread covers row sm, chunks sk..sk+3 (8 chunks of 8 k each = BK 64)
  const int sm = t & 127;
  const int sk = (t >> 7) * 4;
  const unsigned short* arow;
  if (AMODE == 0) {
    arow = Abase + (size_t)idx[m0 + sm] * Dh;
  } else {
    int row = m0 + sm;
    arow = Abase + ((size_t)(row & 255) * NB + (row >> 8)) * Dh;
  }
  const unsigned short* brow = W + (size_t)(n0 + sm) * Dh;

  f32x4 acc[4][4];
#pragma unroll
  for (int i = 0; i < 4; ++i)
#pragma unroll
    for (int j = 0; j < 4; ++j) acc[i][j] = (f32x4)0.f;

  for (int k0 = 0; k0 < Dh; k0 += 64) {
    __syncthreads();  // protect LDS against previous iteration's readers
#pragma unroll
    for (int i = 0; i < 4; ++i) {
      int kc = sk + i;
      *(uint4*)&lds_a[(kc * 128 + sm) * 8] = *(const uint4*)(arow + k0 + kc * 8);
      *(uint4*)&lds_b[(kc * 128 + sm) * 8] = *(const uint4*)(brow + k0 + kc * 8);
    }
    __syncthreads();
#pragma unroll
    for (int q = 0; q < 2; ++q) {
      bf16x8 af[4], bfr[4];
#pragma unroll
      for (int i = 0; i < 4; ++i)
        af[i] = *(const bf16x8*)&lds_a[((q * 4 + lh) * 128 + mq + i * 16 + l15) * 8];
#pragma unroll
      for (int j = 0; j < 4; ++j)
        bfr[j] = *(const bf16x8*)&lds_b[((q * 4 + lh) * 128 + nq + j * 16 + l15) * 8];
#pragma unroll
      for (int i = 0; i < 4; ++i)
#pragma unroll
        for (int j = 0; j < 4; ++j)
          acc[i][j] = __builtin_amdgcn_mfma_f32_16x16x32_bf16(af[i], bfr[j], acc[i][j], 0, 0, 0);
    }
  }

  // epilogue: D[(lh*4+r)][l15] per 16x16 tile
#pragma unroll
  for (int j = 0; j < 4; ++j) {
    const int col = n0 + nq + j * 16 + l15;
    const float bv = bias[col];
#pragma unroll
    for (int i = 0; i < 4; ++i) {
#pragma unroll
      for (int r = 0; r < 4; ++r) {
        const size_t row = (size_t)m0 + mq + i * 16 + lh * 4 + r;
        const float v = acc[i][j][r] + bv;
        if (OUTBF16)
          ((unsigned short*)Cout)[row * N + col] = f2bf(v);
        else
          ((float*)Cout)[row * N + col] = v;
      }
    }
  }
}

// Persistent GRU phase: 256 WGs (1/CU) x 256 thr, nsteps steps, grid barrier
// between steps. WG owns 32 b x 16 d (x3 gates). Whh slice staged to LDS once,
// B-fragments hoisted to registers. fp32 h lives in epilogue-thread registers
// across all steps; only bf16 h round-trips global (ping-pong hb0/hb1).
__global__ __launch_bounds__(256) void gru_phase(
    const unsigned short* __restrict__ W,    // Whh bf16 [1536][512] native
    const unsigned short* __restrict__ gi,   // bf16 [NB][seq=256][1536] (incl. bih)
    const float* __restrict__ bhh,
    unsigned short* __restrict__ hb0,        // bf16 h ping  [NB][Dh]
    unsigned short* __restrict__ hb1,        // bf16 h pong
    const float* __restrict__ h0_in,         // fp32 h init (null -> zeros)
    float* __restrict__ h_final,             // fp32 h out at last step (or null)
    unsigned short* __restrict__ hb_all,     // decoder archive [t][b][d] (or null)
    unsigned int* __restrict__ counter,      // grid barrier counter (pre-zeroed)
    int nsteps) {
  __shared__ unsigned short lds_w[64 * 48 * 8];  // [kc][c][8] = 48 KB
  __shared__ float lds_red[4 * 6 * 256];         // 24 KB
  const int t = threadIdx.x;
  const int bid = blockIdx.x;
  const int d0 = (bid & 31) * 16;
  const int b0 = (bid >> 5) * 32;
  const int w = t >> 6, l = t & 63;
  const int l15 = l & 15, lh = l >> 4;

  // ---- stage Whh slice once: 48 c-cols (3 gates x 16 d) x 512 k ----
#pragma unroll
  for (int i = 0; i < 12; ++i) {
    int id = i * 256 + t;
    int kc = id & 63, c = id >> 6;
    int gate = c >> 4, dl_ = c & 15;
    const unsigned short* src = W + (size_t)(gate * Dh + d0 + dl_) * Dh + kc * 8;
    *(uint4*)&lds_w[(kc * 48 + c) * 8] = *(const uint4*)src;
  }
  __syncthreads();

  // ---- hoist B-fragments to registers (loop-invariant) ----
  bf16x8 bfr[4][3];
#pragma unroll
  for (int q = 0; q < 4; ++q) {
    const int kc32 = w * 4 + q;
#pragma unroll
    for (int nj = 0; nj < 3; ++nj)
      bfr[q][nj] = *(const bf16x8*)&lds_w[((kc32 * 4 + lh) * 48 + nj * 16 + l15) * 8];
  }

  // ---- epilogue-role constants (step-invariant) ----
  const int bl = t >> 3;
  const int dl = (t & 7) * 2;
  const int mi_e = bl >> 4, row_e = bl & 15;
  const int b = b0 + bl;
  const int d = d0 + dl;
  const float2 br = *(const float2*)&bhh[d];
  const float2 bz = *(const float2*)&bhh[Dh + d];
  const float2 bn = *(const float2*)&bhh[2 * Dh + d];
  float2 hp;
  if (h0_in) hp = *(const float2*)&h0_in[(size_t)b * Dh + d];
  else { hp.x = 0.f; hp.y = 0.f; }

  // A-frag byte offsets (step-invariant; wave covers k quarter w*128..+127)
  size_t aoff[2];
#pragma unroll
  for (int mi = 0; mi < 2; ++mi)
    aoff[mi] = (size_t)(b0 + mi * 16 + l15) * Dh + w * 128 + lh * 8;

  // preload gi for step 0
  const unsigned short* gbase = gi + (size_t)b * 256 * G3;
  ushort2 ur = *(const ushort2*)&gbase[d];
  ushort2 uz = *(const ushort2*)&gbase[Dh + d];
  ushort2 un = *(const ushort2*)&gbase[2 * Dh + d];

  for (int s = 0; s < nsteps; ++s) {
    const unsigned short* hin = (s & 1) ? hb1 : hb0;
    unsigned short* hout = (s & 1) ? hb0 : hb1;

    f32x4 acc[2][3];
#pragma unroll
    for (int mi = 0; mi < 2; ++mi)
#pragma unroll
      for (int nj = 0; nj < 3; ++nj) acc[mi][nj] = (f32x4)0.f;

#pragma unroll
    for (int q = 0; q < 4; ++q) {
      bf16x8 a[2];
#pragma unroll
      for (int mi = 0; mi < 2; ++mi)
        a[mi] = *(const bf16x8*)(hin + aoff[mi] + q * 32);
#pragma unroll
      for (int mi = 0; mi < 2; ++mi)
#pragma unroll
        for (int nj = 0; nj < 3; ++nj)
          acc[mi][nj] = __builtin_amdgcn_mfma_f32_16x16x32_bf16(a[mi], bfr[q][nj], acc[mi][nj], 0, 0, 0);
    }

    __syncthreads();  // previous step's lds_red reads are done
#pragma unroll
    for (int mi = 0; mi < 2; ++mi)
#pragma unroll
      for (int nj = 0; nj < 3; ++nj)
#pragma unroll
        for (int r = 0; r < 4; ++r)
          lds_red[(w * 6 + mi * 3 + nj) * 256 + (lh * 4 + r) * 16 + l15] = acc[mi][nj][r];
    __syncthreads();

    // reduce 4 waves + gate math on (b, d..d+1)
    float gh[3][2];
#pragma unroll
    for (int g = 0; g < 3; ++g)
#pragma unroll
      for (int dd = 0; dd < 2; ++dd) {
        float ssum = 0.f;
#pragma unroll
        for (int ww = 0; ww < 4; ++ww)
          ssum += lds_red[(ww * 6 + mi_e * 3 + g) * 256 + row_e * 16 + dl + dd];
        gh[g][dd] = ssum;
      }

    const float gir[2] = {bf2f(ur.x), bf2f(ur.y)};
    const float giz[2] = {bf2f(uz.x), bf2f(uz.y)};
    const float gin[2] = {bf2f(un.x), bf2f(un.y)};
    const float brv[2] = {br.x, br.y}, bzv[2] = {bz.x, bz.y}, bnv[2] = {bn.x, bn.y};
    float hpv[2] = {hp.x, hp.y};
    float o[2];
#pragma unroll
    for (int dd = 0; dd < 2; ++dd) {
      float rr = 1.f / (1.f + expf(-(gir[dd] + gh[0][dd] + brv[dd])));
      float zz = 1.f / (1.f + expf(-(giz[dd] + gh[1][dd] + bzv[dd])));
      float nn = tanhf(gin[dd] + rr * (gh[2][dd] + bnv[dd]));
      o[dd] = (1.f - zz) * nn + zz * hpv[dd];
    }
    hp.x = o[0]; hp.y = o[1];

    ushort2 ob; ob.x = f2bf(o[0]); ob.y = f2bf(o[1]);
    *(ushort2*)&hout[(size_t)b * Dh + d] = ob;
    if (hb_all) *(ushort2*)&hb_all[((size_t)s * NB + b) * Dh + d] = ob;
    if (h_final && s == nsteps - 1) *(float2*)&h_final[(size_t)b * Dh + d] = hp;

    // prefetch gi for next step (independent of h -> hides under barrier)
    if (s + 1 < nsteps) {
      const unsigned short* gr = gbase + (size_t)(s + 1) * G3;
      ur = *(const ushort2*)&gr[d];
      uz = *(const ushort2*)&gr[Dh + d];
      un = *(const ushort2*)&gr[2 * Dh + d];
    }

    // ---- grid barrier (skip after last step) ----
    if (s + 1 < nsteps) {
      __syncthreads();
      if (t == 0) {
        __hip_atomic_fetch_add(counter, 1u, __ATOMIC_RELEASE, __HIP_MEMORY_SCOPE_AGENT);
        const unsigned int tgt = 256u * (unsigned)(s + 1);
        while (__hip_atomic_load(counter, __ATOMIC_ACQUIRE, __HIP_MEMORY_SCOPE_AGENT) < tgt) {}
      }
      __syncthreads();
    }
  }
}

// in-place log_softmax over last dim (512); one wave per row
__global__ __launch_bounds__(256) void logsoftmax512(float* __restrict__ x) {
  const int row = blockIdx.x * 4 + (threadIdx.x >> 6);
  const int lane = threadIdx.x & 63;
  float* p = x + (size_t)row * NV + lane * 8;
  float4 v0 = *(const float4*)p;
  float4 v1 = *(const float4*)(p + 4);
  float m = fmaxf(fmaxf(fmaxf(v0.x, v0.y), fmaxf(v0.z, v0.w)),
                  fmaxf(fmaxf(v1.x, v1.y), fmaxf(v1.z, v1.w)));
#pragma unroll
  for (int o = 1; o < 64; o <<= 1) m = fmaxf(m, __shfl_xor(m, o, 64));
  float s = expf(v0.x - m) + expf(v0.y - m) + expf(v0.z - m) + expf(v0.w - m) +
            expf(v1.x - m) + expf(v1.y - m) + expf(v1.z - m) + expf(v1.w - m);
#pragma unroll
  for (int o = 1; o < 64; o <<= 1) s += __shfl_xor(s, o, 64);
  const float ls = m + logf(s);
  v0.x -= ls; v0.y -= ls; v0.z -= ls; v0.w -= ls;
  v1.x -= ls; v1.y -= ls; v1.z -= ls; v1.w -= ls;
  *(float4*)p = v0;
  *(float4*)(p + 4) = v1;
}

extern "C" void kernel_launch(void* const* d_in, const int* in_sizes, int n_in,
                              void* d_out, int out_size, void* d_ws, size_t ws_size,
                              hipStream_t stream) {
  (void)in_sizes; (void)n_in; (void)out_size; (void)ws_size;
  const int* src = (const int*)d_in[0];
  const int* trg = (const int*)d_in[1];
  const float* enc_emb = (const float*)d_in[4];
  const float* enc_Wih = (const float*)d_in[5];
  const float* enc_Whh = (const float*)d_in[6];
  const float* enc_bih = (const float*)d_in[7];
  const float* enc_bhh = (const float*)d_in[8];
  const float* dec_emb = (const float*)d_in[9];
  const float* dec_Wih = (const float*)d_in[10];
  const float* dec_Whh = (const float*)d_in[11];
  const float* dec_bih = (const float*)d_in[12];
  const float* dec_bhh = (const float*)d_in[13];
  const float* out_W = (const float*)d_in[14];
  const float* out_b = (const float*)d_in[15];

  char* ws = (char*)d_ws;
  size_t off = 0;
  auto alloc = [&](size_t bytes) -> char* {
    char* p = ws + off;
    off += (bytes + 255) & ~(size_t)255;
    return p;
  };
  typedef unsigned short u16;
  u16* gi = (u16*)alloc((size_t)NB * SL * G3 * 2);        // 201 MB (reused enc->dec)
  u16* hb_all = (u16*)alloc((size_t)TL * NB * Dh * 2);    // 67 MB decoder bf16 h
  u16* hb0 = (u16*)alloc((size_t)NB * Dh * 2);
  u16* hb1 = (u16*)alloc((size_t)NB * Dh * 2);
  float* h_enc = (float*)alloc((size_t)NB * Dh * 4);
  u16* embB_e = (u16*)alloc((size_t)NV * Dh * 2);
  u16* embB_d = (u16*)alloc((size_t)NV * Dh * 2);         // relu pre-applied
  u16* WihB_e = (u16*)alloc((size_t)G3 * Dh * 2);
  u16* WhhB_e = (u16*)alloc((size_t)G3 * Dh * 2);
  u16* WihB_d = (u16*)alloc((size_t)G3 * Dh * 2);
  u16* WhhB_d = (u16*)alloc((size_t)G3 * Dh * 2);
  u16* outWB = (u16*)alloc((size_t)NV * Dh * 2);
  unsigned int* ctr = (unsigned int*)alloc(256);          // [0]=enc, [1]=dec

  // ---- one-time conversions (weights stay in native [N][K] layout) ----
  cvt_bf16<<<(NV * Dh / 4 + 255) / 256, 256, 0, stream>>>(enc_emb, embB_e, NV * Dh / 4, 0);
  cvt_bf16<<<(NV * Dh / 4 + 255) / 256, 256, 0, stream>>>(dec_emb, embB_d, NV * Dh / 4, 1);
  cvt_bf16<<<(G3 * Dh / 4 + 255) / 256, 256, 0, stream>>>(enc_Wih, WihB_e, G3 * Dh / 4, 0);
  cvt_bf16<<<(G3 * Dh / 4 + 255) / 256, 256, 0, stream>>>(enc_Whh, WhhB_e, G3 * Dh / 4, 0);
  cvt_bf16<<<(G3 * Dh / 4 + 255) / 256, 256, 0, stream>>>(dec_Wih, WihB_d, G3 * Dh / 4, 0);
  cvt_bf16<<<(G3 * Dh / 4 + 255) / 256, 256, 0, stream>>>(dec_Whh, WhhB_d, G3 * Dh / 4, 0);
  cvt_bf16<<<(NV * Dh / 4 + 255) / 256, 256, 0, stream>>>(out_W, outWB, NV * Dh / 4, 0);
  hipMemsetAsync(hb0, 0, (size_t)NB * Dh * 2, stream);    // h0 = 0 (bf16)
  hipMemsetAsync(ctr, 0, 8, stream);                      // reset both barrier counters

  // ---- encoder gi = emb[src] @ Wih^T + bih (bf16 out) ----
  dim3 ggi(G3 / 128, NB * SL / 128);
  gemm_bf16<0, true><<<ggi, 256, 0, stream>>>(embB_e, src, WihB_e, enc_bih, gi, G3);

  // ---- encoder recurrence: one persistent cooperative kernel, 256 steps ----
  int ns = 256;
  {
    const u16* Wp = WhhB_e; const u16* gip = gi; const float* bp = enc_bhh;
    u16* p0 = hb0; u16* p1 = hb1;
    const float* h0n = nullptr; float* hf = h_enc; u16* hba = nullptr;
    unsigned int* c0 = ctr;
    void* args[] = {&Wp, &gip, &bp, &p0, &p1, &h0n, &hf, &hba, &c0, &ns};
    hipLaunchCooperativeKernel((void*)gru_phase, dim3(256), dim3(256), args, 0, stream);
  }

  // ---- decoder gi = relu(emb[trg]) @ Wih^T + bih (overwrites gi) ----
  gemm_bf16<0, true><<<ggi, 256, 0, stream>>>(embB_d, trg, WihB_d, dec_bih, gi, G3);

  // ---- decoder recurrence (continues from h_enc; hb0 holds its bf16 mirror) ----
  {
    const u16* Wp = WhhB_d; const u16* gip = gi; const float* bp = dec_bhh;
    u16* p0 = hb0; u16* p1 = hb1;
    const float* h0n = h_enc; float* hf = nullptr; u16* hba = hb_all;
    unsigned int* c1 = ctr + 1;
    void* args[] = {&Wp, &gip, &bp, &p0, &p1, &h0n, &hf, &hba, &c1, &ns};
    hipLaunchCooperativeKernel((void*)gru_phase, dim3(256), dim3(256), args, 0, stream);
  }

  // ---- logits = hb_all @ out_W^T + out_b -> d_out (fp32), then log_softmax ----
  dim3 glg(NV / 128, NB * TL / 128);
  gemm_bf16<1, false><<<glg, 256, 0, stream>>>(hb_all, nullptr, outWB, out_b, d_out, NV);
  logsoftmax512<<<NB * TL / 4, 256, 0, stream>>>((float*)d_out);
}